// Round 10
// baseline (123.079 us; speedup 1.0000x reference)
//
#include <hip/hip_runtime.h>
#include <math.h>

// Deepmd angular descriptor, f32 in / f32 out. B=8, N=4096, M=96, OUT_W=384.
//
// R10 vs R9 (~37 us): remove the two remaining serializers.
//  - NO __threadfence_block: rare nonzero items (mean 0.43/pair) are merged
//    into the zero row IN REGISTERS via __ballot + __shfl (ranks of nonzero
//    items are distinct, so no collisions), then ONE full-wave coalesced
//    store per row (b128 + b64). No pre-zero store, no partial-line scatter
//    -> no vmcnt drains, no write-allocate fetches, WRITE exactly 49152 KB.
//  - positions staged padded to float4 in LDS (64 KB): gather = 1 ds_read_b128
//    instead of 3 ds_read_b32.
// block = 1024 thr = 16 waves, 1 pair/wave-iter, NITER=4 -> 64 pairs/block;
// grid = 512 = 2 blocks/CU (LDS 70 KB/block); single __syncthreads (stage).
#define M_NB   96
#define OUT_W  384
#define NATOM  4096
#define WPB    16
#define NITER  4

// fold one rare item (row floats [base, base+3)) into this lane's slots:
// float4 owns [4*lane, 4*lane+4), float2 owns [256+2*lane, 256+2*lane+2)
__device__ __forceinline__ void merge3(float4& a4, float2& a2, int base,
                                       float v0, float v1, float v2, int lane)
{
    const int f4lo = 4 * lane;
    const int f2lo = 256 + 2 * lane;
    const float v[3] = {v0, v1, v2};
    #pragma unroll
    for (int t = 0; t < 3; ++t) {
        const int idx = base + t;
        if      (idx == f4lo)     a4.x = v[t];
        else if (idx == f4lo + 1) a4.y = v[t];
        else if (idx == f4lo + 2) a4.z = v[t];
        else if (idx == f4lo + 3) a4.w = v[t];
        else if (idx == f2lo)     a2.x = v[t];
        else if (idx == f2lo + 1) a2.y = v[t];
    }
}

__global__ __launch_bounds__(64 * WPB, 8) void deepmd_angular_kernel(
    const float* __restrict__ positions,  // [B,N,3]
    const float* __restrict__ cell,       // [B,3,3]
    const float* __restrict__ offsets,    // [B,N,M,3]
    const float* __restrict__ mask,       // [B,N,M]
    const int*   __restrict__ neighbors,  // [B,N,M]
    float*       __restrict__ out,        // [B,N,OUT_W]
    int N)
{
    __shared__ float4 pos4_s[NATOM];        // 64 KB padded position table
    __shared__ float  cut_s[WPB][M_NB];     // 6 KB per-wave cut exchange

    const int tid  = threadIdx.x;
    const int wv   = tid >> 6;
    const int lane = tid & 63;
    const bool low = lane < 32;

    const int p0 = blockIdx.x * (WPB * NITER);   // first pair of block
    const int b  = p0 / N;                       // uniform (64 | N)

    // ---- stage batch positions -> LDS, padded to 16 B/atom ----
    {
        const float* pb_ = positions + (size_t)b * N * 3;
        for (int a = tid; a < NATOM; a += 64 * WPB) {
            const float3 v = *(const float3*)(pb_ + 3 * a);
            pos4_s[a] = make_float4(v.x, v.y, v.z, 0.f);
        }
    }
    __syncthreads();                             // only barrier in the kernel

    const float* cb = cell + (size_t)b * 9;      // uniform -> scalar loads
    const float c00 = cb[0], c01 = cb[1], c02 = cb[2];
    const float c10 = cb[3], c11 = cb[4], c12 = cb[5];
    const float c20 = cb[6], c21 = cb[7], c22 = cb[8];

    #pragma unroll
    for (int it = 0; it < NITER; ++it) {
        const int q  = p0 + wv * NITER + it;     // this wave's pair
        const int nn = q - b * N;                // local atom index

        // ---- inputs: item A (m=lane) all lanes, item B (m=64+lane) low lanes
        const long eA = (long)q * M_NB + lane;
        const int    jA = neighbors[eA];
        const float mkA = mask[eA];
        const float3 oA = *(const float3*)(offsets + eA * 3);

        int jB = 0; float mkB = 0.f; float3 oB = make_float3(0.f, 0.f, 0.f);
        if (low) {
            const long eB = eA + 64;
            jB  = neighbors[eB];
            mkB = mask[eB];
            oB  = *(const float3*)(offsets + eB * 3);
        }

        const float4 pi  = pos4_s[nn];           // wave-uniform b128 broadcast
        const float4 pjA = pos4_s[jA];           // 1 x ds_read_b128 gather

        const float dxA = pjA.x - pi.x + oA.x * c00 + oA.y * c10 + oA.z * c20;
        const float dyA = pjA.y - pi.y + oA.x * c01 + oA.y * c11 + oA.z * c21;
        const float dzA = pjA.z - pi.z + oA.x * c02 + oA.y * c12 + oA.z * c22;
        const float dA  = sqrtf(dxA * dxA + dyA * dyA + dzA * dzA + 1e-12f);
        float cutA = 0.f;
        if (mkA != 0.f && dA < 6.f)
            cutA = 0.5f * (cosf(dA * 0.52359877559829887f) + 1.f) / dA;

        float dxB = 0.f, dyB = 0.f, dzB = 0.f, cutB = 0.f;
        if (low) {
            const float4 pjB = pos4_s[jB];
            dxB = pjB.x - pi.x + oB.x * c00 + oB.y * c10 + oB.z * c20;
            dyB = pjB.y - pi.y + oB.x * c01 + oB.y * c11 + oB.z * c21;
            dzB = pjB.z - pi.z + oB.x * c02 + oB.y * c12 + oB.z * c22;
            const float dB = sqrtf(dxB * dxB + dyB * dyB + dzB * dzB + 1e-12f);
            if (mkB != 0.f && dB < 6.f)
                cutB = 0.5f * (cosf(dB * 0.52359877559829887f) + 1.f) / dB;
        }

        // ---- wave-local cut exchange (same-wave DS ordering) ----
        cut_s[wv][lane] = cutA;
        if (low) cut_s[wv][64 + lane] = cutB;

        // ---- rare lanes compute stable rank + weighted vec ----
        // rank(m) = #{k: cut_k > cut_m} + #{k<m: cut_k == cut_m}; distinct
        // across nonzero items. Zero items contribute exact zeros.
        int rkA = 0; float w0A = 0.f, w1A = 0.f, w2A = 0.f;
        if (cutA != 0.f) {
            const int mA = lane;
            int rank = 0;
            const float4* c4 = (const float4*)cut_s[wv];
            #pragma unroll
            for (int k4 = 0; k4 < M_NB / 4; ++k4) {
                const float4 c = c4[k4];         // ds_read_b128 broadcast
                const int k = 4 * k4;
                rank += (c.x > cutA) || (c.x == cutA && k + 0 < mA);
                rank += (c.y > cutA) || (c.y == cutA && k + 1 < mA);
                rank += (c.z > cutA) || (c.z == cutA && k + 2 < mA);
                rank += (c.w > cutA) || (c.w == cutA && k + 3 < mA);
            }
            rkA = rank; w0A = cutA * dxA; w1A = cutA * dyA; w2A = cutA * dzA;
        }
        int rkB = 0; float w0B = 0.f, w1B = 0.f, w2B = 0.f;
        if (low && cutB != 0.f) {
            const int mB = 64 + lane;
            int rank = 0;
            const float4* c4 = (const float4*)cut_s[wv];
            #pragma unroll
            for (int k4 = 0; k4 < M_NB / 4; ++k4) {
                const float4 c = c4[k4];
                const int k = 4 * k4;
                rank += (c.x > cutB) || (c.x == cutB && k + 0 < mB);
                rank += (c.y > cutB) || (c.y == cutB && k + 1 < mB);
                rank += (c.z > cutB) || (c.z == cutB && k + 2 < mB);
                rank += (c.w > cutB) || (c.w == cutB && k + 3 < mB);
            }
            rkB = rank; w0B = cutB * dxB; w1B = cutB * dyB; w2B = cutB * dzB;
        }

        // ---- register merge: uniform loop over nonzero items (mean 0.43) ----
        unsigned long long bmA = __ballot(cutA != 0.f);
        unsigned long long bmB = __ballot(low && cutB != 0.f);
        float4 a4 = make_float4(0.f, 0.f, 0.f, 0.f);
        float2 a2 = make_float2(0.f, 0.f);
        while (bmA) {
            const int src = (int)__builtin_ctzll(bmA); bmA &= bmA - 1;
            const int   r  = __shfl(rkA, src);
            const float v0 = __shfl(w0A, src);
            const float v1 = __shfl(w1A, src);
            const float v2 = __shfl(w2A, src);
            merge3(a4, a2, 3 * r, v0, v1, v2, lane);
        }
        while (bmB) {
            const int src = (int)__builtin_ctzll(bmB); bmB &= bmB - 1;
            const int   r  = __shfl(rkB, src);
            const float v0 = __shfl(w0B, src);
            const float v1 = __shfl(w1B, src);
            const float v2 = __shfl(w2B, src);
            merge3(a4, a2, 3 * r, v0, v1, v2, lane);
        }

        // ---- single full-wave coalesced row store (1536 B) ----
        float* rowp = out + (size_t)q * OUT_W;
        ((float4*)rowp)[lane] = a4;              // floats   0..255
        ((float2*)(rowp + 256))[lane] = a2;      // floats 256..383
    }
}

extern "C" void kernel_launch(void* const* d_in, const int* in_sizes, int n_in,
                              void* d_out, int out_size, void* d_ws, size_t ws_size,
                              hipStream_t stream) {
    const float* positions = (const float*)d_in[0];
    const float* cell      = (const float*)d_in[1];
    const float* offsets   = (const float*)d_in[2];
    const float* mask      = (const float*)d_in[3];
    const int*   neighbors = (const int*)d_in[4];
    float*       out       = (float*)d_out;

    const int BN = in_sizes[0] / 3;        // B*N = 32768
    const int B  = in_sizes[1] / 9;        // 8
    const int N  = BN / B;                 // 4096

    dim3 block(64 * WPB, 1, 1);            // 1024 threads = 16 waves
    dim3 grid(BN / (WPB * NITER), 1, 1);   // 512 blocks = 2/CU resident
    deepmd_angular_kernel<<<grid, block, 0, stream>>>(
        positions, cell, offsets, mask, neighbors, out, N);
}

// Round 11
// 118.387 us; speedup vs baseline: 1.0396x; 1.0396x over previous
//
#include <hip/hip_runtime.h>
#include <math.h>

// Deepmd angular descriptor, f32 in / f32 out. B=8, N=4096, M=96, OUT_W=384.
//
// R11 vs R10 (~36 us, neutral to fence removal): delete the LDS cut
// round-trip. Ranking is now fully in-register: the wave holds all 96 cuts
// (cutA = m 0..63 on lanes, cutB = m 64..95 on low lanes); each rare nonzero
// item (mean 0.43/pair, found via 2 ballots) gets
//   rank = popc(ballot(cutA>c)) + popc(ballot(cutB>c)) + stable-tie masks
// computed wave-uniform in SALU -- no ds_write/ds_read chain, no lgkmcnt
// waits in the epilogue. LDS holds only the float4 position table (64 KB).
// __cosf (v_cos_f32) replaces libm cosf in the if-converted cut body.
// block = 1024 thr = 16 waves, NITER=4 pairs/wave; grid 512 = 2 blocks/CU.
#define M_NB   96
#define OUT_W  384
#define NATOM  4096
#define WPB    16
#define NITER  4

// fold one item (row floats [base,base+3)) into this lane's output slots:
// float4 owns [4*lane,4*lane+4), float2 owns [256+2*lane,256+2*lane+2)
__device__ __forceinline__ void merge3(float4& a4, float2& a2, int base,
                                       float v0, float v1, float v2, int lane)
{
    const int f4lo = 4 * lane;
    const int f2lo = 256 + 2 * lane;
    const float v[3] = {v0, v1, v2};
    #pragma unroll
    for (int t = 0; t < 3; ++t) {
        const int idx = base + t;
        if      (idx == f4lo)     a4.x = v[t];
        else if (idx == f4lo + 1) a4.y = v[t];
        else if (idx == f4lo + 2) a4.z = v[t];
        else if (idx == f4lo + 3) a4.w = v[t];
        else if (idx == f2lo)     a2.x = v[t];
        else if (idx == f2lo + 1) a2.y = v[t];
    }
}

__global__ __launch_bounds__(64 * WPB, 8) void deepmd_angular_kernel(
    const float* __restrict__ positions,  // [B,N,3]
    const float* __restrict__ cell,       // [B,3,3]
    const float* __restrict__ offsets,    // [B,N,M,3]
    const float* __restrict__ mask,       // [B,N,M]
    const int*   __restrict__ neighbors,  // [B,N,M]
    float*       __restrict__ out,        // [B,N,OUT_W]
    int N)
{
    __shared__ float4 pos4_s[NATOM];        // 64 KB padded position table

    const int tid  = threadIdx.x;
    const int wv   = tid >> 6;
    const int lane = tid & 63;
    const bool low = lane < 32;

    const int p0 = blockIdx.x * (WPB * NITER);   // first pair of block
    const int b  = p0 / N;                       // uniform (64 | N)

    // ---- stage batch positions -> LDS (padded to 16 B/atom) ----
    {
        const float* pb_ = positions + (size_t)b * N * 3;
        for (int a = tid; a < NATOM; a += 64 * WPB) {
            const float3 v = *(const float3*)(pb_ + 3 * a);
            pos4_s[a] = make_float4(v.x, v.y, v.z, 0.f);
        }
    }
    __syncthreads();                             // only barrier in the kernel

    const float* cb = cell + (size_t)b * 9;      // uniform -> scalar loads
    const float c00 = cb[0], c01 = cb[1], c02 = cb[2];
    const float c10 = cb[3], c11 = cb[4], c12 = cb[5];
    const float c20 = cb[6], c21 = cb[7], c22 = cb[8];

    #pragma unroll
    for (int it = 0; it < NITER; ++it) {
        const int q  = p0 + wv * NITER + it;     // this wave's pair
        const int nn = q - b * N;                // local atom index

        // ---- stream inputs: item A (m=lane), item B (m=64+lane, low lanes)
        const long eA = (long)q * M_NB + lane;
        const int    jA = neighbors[eA];
        const float mkA = mask[eA];
        const float3 oA = *(const float3*)(offsets + eA * 3);

        int jB = 0; float mkB = 0.f; float3 oB = make_float3(0.f, 0.f, 0.f);
        if (low) {
            const long eB = eA + 64;
            jB  = neighbors[eB];
            mkB = mask[eB];
            oB  = *(const float3*)(offsets + eB * 3);
        }

        const float4 pi  = pos4_s[nn];           // uniform b128 broadcast
        const float4 pjA = pos4_s[jA];           // 1 x ds_read_b128 gather

        const float dxA = pjA.x - pi.x + oA.x * c00 + oA.y * c10 + oA.z * c20;
        const float dyA = pjA.y - pi.y + oA.x * c01 + oA.y * c11 + oA.z * c21;
        const float dzA = pjA.z - pi.z + oA.x * c02 + oA.y * c12 + oA.z * c22;
        const float dA  = sqrtf(dxA * dxA + dyA * dyA + dzA * dzA + 1e-12f);
        float cutA = 0.f;
        if (mkA != 0.f && dA < 6.f)
            cutA = 0.5f * (__cosf(dA * 0.52359877559829887f) + 1.f) / dA;

        float dxB = 0.f, dyB = 0.f, dzB = 0.f, cutB = 0.f;
        if (low) {
            const float4 pjB = pos4_s[jB];
            dxB = pjB.x - pi.x + oB.x * c00 + oB.y * c10 + oB.z * c20;
            dyB = pjB.y - pi.y + oB.x * c01 + oB.y * c11 + oB.z * c21;
            dzB = pjB.z - pi.z + oB.x * c02 + oB.y * c12 + oB.z * c22;
            const float dB = sqrtf(dxB * dxB + dyB * dyB + dzB * dzB + 1e-12f);
            if (mkB != 0.f && dB < 6.f)
                cutB = 0.5f * (__cosf(dB * 0.52359877559829887f) + 1.f) / dB;
        }

        // cut-weighted vectors (cheap, all lanes)
        const float w0A = cutA * dxA, w1A = cutA * dyA, w2A = cutA * dzA;
        const float w0B = cutB * dxB, w1B = cutB * dyB, w2B = cutB * dzB;

        // ---- in-register stable rank + merge (no LDS, no fences) ----
        // rank(m) = #{k: cut_k > cut_m} + #{k<m: cut_k == cut_m}
        float4 a4 = make_float4(0.f, 0.f, 0.f, 0.f);
        float2 a2 = make_float2(0.f, 0.f);

        unsigned long long t = __ballot(cutA != 0.f);
        while (t) {
            const int s = (int)__builtin_ctzll(t); t &= t - 1;   // item m = s
            const float c = __shfl(cutA, s);
            const unsigned long long gtA = __ballot(cutA > c);
            const unsigned long long gtB = __ballot(cutB > c);
            const unsigned long long eqA = __ballot(cutA == c);
            // B-ties have k>=64 > m=s -> excluded
            const int rank = __popcll(gtA) + __popcll(gtB)
                           + __popcll(eqA & ((1ull << s) - 1ull));
            merge3(a4, a2, 3 * rank,
                   __shfl(w0A, s), __shfl(w1A, s), __shfl(w2A, s), lane);
        }
        t = __ballot(cutB != 0.f);
        while (t) {
            const int s = (int)__builtin_ctzll(t); t &= t - 1;   // item m = 64+s
            const float c = __shfl(cutB, s);
            const unsigned long long gtA = __ballot(cutA > c);
            const unsigned long long gtB = __ballot(cutB > c);
            const unsigned long long eqA = __ballot(cutA == c);  // all k<64 < m
            const unsigned long long eqB = __ballot(cutB == c);
            const int rank = __popcll(gtA) + __popcll(gtB) + __popcll(eqA)
                           + __popcll(eqB & ((1ull << s) - 1ull));
            merge3(a4, a2, 3 * rank,
                   __shfl(w0B, s), __shfl(w1B, s), __shfl(w2B, s), lane);
        }

        // ---- single full-wave coalesced row store (1536 B) ----
        float* rowp = out + (size_t)q * OUT_W;
        ((float4*)rowp)[lane] = a4;              // floats   0..255
        ((float2*)(rowp + 256))[lane] = a2;      // floats 256..383
    }
}

extern "C" void kernel_launch(void* const* d_in, const int* in_sizes, int n_in,
                              void* d_out, int out_size, void* d_ws, size_t ws_size,
                              hipStream_t stream) {
    const float* positions = (const float*)d_in[0];
    const float* cell      = (const float*)d_in[1];
    const float* offsets   = (const float*)d_in[2];
    const float* mask      = (const float*)d_in[3];
    const int*   neighbors = (const int*)d_in[4];
    float*       out       = (float*)d_out;

    const int BN = in_sizes[0] / 3;        // B*N = 32768
    const int B  = in_sizes[1] / 9;        // 8
    const int N  = BN / B;                 // 4096

    dim3 block(64 * WPB, 1, 1);            // 1024 threads = 16 waves
    dim3 grid(BN / (WPB * NITER), 1, 1);   // 512 blocks = 2/CU resident
    deepmd_angular_kernel<<<grid, block, 0, stream>>>(
        positions, cell, offsets, mask, neighbors, out, N);
}